// Round 9
// baseline (152.609 us; speedup 1.0000x reference)
//
#include <hip/hip_runtime.h>
#include <hip/hip_bf16.h>

typedef unsigned short u16;
typedef __attribute__((ext_vector_type(8))) short short8;
typedef __attribute__((ext_vector_type(4))) float float4v;
typedef __attribute__((ext_vector_type(16))) float float16v;

#define BATCH 8
#define SLEN  200
#define NNODE 512
#define C1    32
#define C2    64
#define NEDGE 2048
#define NEGV  -9000000000000000.0f

#define H1S 40    // h1p row stride in bf16 (80 B, 16B-aligned)
#define H1R 232   // 2 pad + 200 data + 30 pad (covers 32-row tile 6 + taps)
#define A1S 40    // im2col row stride in bf16 (80 B -> 20-dword bank shift/row)

__device__ __forceinline__ u16 f2bf(float f) {
    unsigned int x = __float_as_uint(f);
    unsigned int lsb = (x >> 16) & 1u;
    x += 0x7fffu + lsb;
    return (u16)(x >> 16);
}

__device__ __forceinline__ float bf2f(u16 u) {
    return __uint_as_float(((unsigned int)u) << 16);
}

// packed f32x2 -> bf16x2, RNE
__device__ __forceinline__ unsigned int pk2(float a, float b) {
    __hip_bfloat162 h = __float22bfloat162_rn(make_float2(a, b));
    unsigned int r;
    __builtin_memcpy(&r, &h, 4);
    return r;
}

// ---------------------------------------------------------------------------
// Kernel -1: tiled transpose x (B,S,NC) -> xT (B,NC,S), NC = 1024
// ---------------------------------------------------------------------------
__global__ __launch_bounds__(256) void transpose_kernel(
    const float* __restrict__ x,    // (8, 200, 1024)
    float* __restrict__ xT)         // (8, 1024, 200)
{
    __shared__ float tile[32][33];
    const int t   = threadIdx.x;
    const int nc0 = blockIdx.x * 32;
    const int s0  = blockIdx.y * 32;
    const int b   = blockIdx.z;
    const int c   = t & 31, rr = t >> 5;

    #pragma unroll
    for (int r = 0; r < 4; ++r) {
        const int s = s0 + rr + r * 8;
        if (s < SLEN)
            tile[rr + r * 8][c] = x[((size_t)(b * SLEN + s)) * 1024 + nc0 + c];
    }
    __syncthreads();
    #pragma unroll
    for (int r = 0; r < 4; ++r) {
        const int nc = nc0 + rr + r * 8;
        const int s = s0 + c;
        if (s < SLEN)
            xT[((size_t)(b * 1024 + nc)) * SLEN + s] = tile[c][rr + r * 8];
    }
}

// ---------------------------------------------------------------------------
// Kernel 0: pack conv MFMA B-fragments (bf16) into workspace
// w1f: conv1 16x16x32 B-frag. k 0..9: w_hi; 10..19: w_hi; 20..29: w_lo; pad 0
// w2f: conv2 32x32x16 B-frags, fid = (kk*2+kc)*2+nt:
//   lane l: oc = nt*32+(l&31); k-slot j -> h1p col c = kc*16+(l>>5)*8+j,
//   ic = (c&1)*16 + (c>>1)   (interleaved h1p layout)
// ---------------------------------------------------------------------------
__global__ __launch_bounds__(256) void prep_kernel(
    const float* __restrict__ w1,   // (32, 2, 5)
    const float* __restrict__ w2,   // (64, 32, 5)
    u16* __restrict__ w1f,          // 2*64*8
    u16* __restrict__ w2f)          // 20*64*8
{
    const int t = threadIdx.x;
    if (t < 128) {
        const int nt = t >> 6;
        const int l  = t & 63;
        const int mml = l & 15, qq = l >> 4;
        const int oc = nt * 16 + mml;
        #pragma unroll
        for (int j = 0; j < 8; ++j) {
            const int k = qq * 8 + j;
            u16 val = 0;
            if (k < 10) {
                val = f2bf(w1[oc * 10 + k]);
            } else if (k < 20) {
                val = f2bf(w1[oc * 10 + (k - 10)]);
            } else if (k < 30) {
                const float wf = w1[oc * 10 + (k - 20)];
                val = f2bf(wf - bf2f(f2bf(wf)));
            }
            w1f[(nt * 64 + l) * 8 + j] = val;
        }
    }
    const int lane = t & 63, wv = t >> 6;
    if (wv == 0) {
        const int l31 = lane & 31, h = lane >> 5;
        #pragma unroll
        for (int kk = 0; kk < 5; ++kk)
            #pragma unroll
            for (int kc = 0; kc < 2; ++kc)
                #pragma unroll
                for (int nt = 0; nt < 2; ++nt) {
                    const int fid = (kk * 2 + kc) * 2 + nt;
                    const int oc  = nt * 32 + l31;
                    #pragma unroll
                    for (int j = 0; j < 8; ++j) {
                        const int c  = kc * 16 + h * 8 + j;
                        const int ic = (c & 1) * 16 + (c >> 1);
                        w2f[(fid * 64 + lane) * 8 + j] =
                            f2bf(w2[(size_t)oc * 160 + ic * 5 + kk]);
                    }
                }
    }
}

// ---------------------------------------------------------------------------
// Kernel 1: conv1(16x16x32) -> relu -> conv2(32x32x16) -> relu -> mean
//           -> Wh1/f1/f2.  one block (256 threads) per (b, n)
// ---------------------------------------------------------------------------
__global__ __launch_bounds__(256) void conv_fused_kernel(
    const float* __restrict__ xT,   // (8, 1024, 200) transposed input
    const float* __restrict__ b1,   // (32,)
    const float* __restrict__ b2,   // (64,)
    const float* __restrict__ W1,   // (64, 64)
    const float* __restrict__ a1,   // (128, 1)
    const u16* __restrict__ w1f,
    const u16* __restrict__ w2f,
    u16* __restrict__ Wh_bt,        // (8, 64, 512) bf16 [b][o][node]
    float* __restrict__ f1,         // (4096,)
    float* __restrict__ f2)         // (4096,)
{
    __shared__ unsigned int xhl[2][212];           // (x_hi | x_lo<<16), idx = s+2
    __shared__ __align__(16) u16 A1[208 * A1S];    // im2col conv1 input
    __shared__ __align__(16) u16 h1p[H1R * H1S];   // conv1 out [s][c], c=2u+v <-> ic=v*16+u
    __shared__ float red[4][64];
    __shared__ float hm[64];
    __shared__ float part[4][64];

    const int t    = threadIdx.x;
    const int blk  = blockIdx.x;
    const int b    = blk >> 9;
    const int n    = blk & 511;
    const int lane = t & 63;
    const int wv   = t >> 6;
    const int ml   = lane & 15;
    const int q    = lane >> 4;
    const int l31  = lane & 31;
    const int h    = lane >> 5;

    // fragments from prepacked global (coalesced 16B, L2-hot)
    const short8 w1frag0 = *(const short8*)(w1f + lane * 8);
    const short8 w1frag1 = *(const short8*)(w1f + (64 + lane) * 8);
    short8 wf[20];
    #pragma unroll
    for (int fid = 0; fid < 20; ++fid)
        wf[fid] = *(const short8*)(w2f + (fid * 64 + lane) * 8);
    const float bias1a = b1[ml];
    const float bias1b = b1[16 + ml];
    const float bias2a = b2[l31];
    const float bias2b = b2[32 + l31];

    // stage x (contiguous reads from xT), split hi/lo, pack; zero pads
    if (t < SLEN) {
        const float x0 = xT[((size_t)(b * 1024 + 2 * n)) * SLEN + t];
        const float x1 = xT[((size_t)(b * 1024 + 2 * n + 1)) * SLEN + t];
        const u16 hx = f2bf(x0), hy = f2bf(x1);
        const u16 lx = f2bf(x0 - bf2f(hx));
        const u16 ly = f2bf(x1 - bf2f(hy));
        xhl[0][2 + t] = (unsigned int)hx | ((unsigned int)lx << 16);
        xhl[1][2 + t] = (unsigned int)hy | ((unsigned int)ly << 16);
    } else if (t < 212) {
        const int p = (t < 202) ? (t - 200) : t;   // 0,1, then 202..211
        xhl[0][p] = 0u;
        xhl[1][p] = 0u;
    }
    // zero h1p pad rows 0,1 (dw 0..39) and 202..231 (dw 4040..4639)
    {
        unsigned int* hz = (unsigned int*)h1p;
        for (int idx = t; idx < 640; idx += 256)
            hz[(idx < 40) ? idx : (4000 + idx)] = 0u;
    }
    __syncthreads();

    // build im2col row m = t (per-thread, 4x b128 stores)
    if (t < 208) {
        unsigned int X0[5], X1[5];
        #pragma unroll
        for (int kk = 0; kk < 5; ++kk) {
            X0[kk] = xhl[0][t + kk];
            X1[kk] = xhl[1][t + kk];
        }
        unsigned int d[16];
        d[0] = (X0[0] & 0xffffu) | (X0[1] << 16);
        d[1] = (X0[2] & 0xffffu) | (X0[3] << 16);
        d[2] = (X0[4] & 0xffffu) | (X1[0] << 16);
        d[3] = (X1[1] & 0xffffu) | (X1[2] << 16);
        d[4] = (X1[3] & 0xffffu) | (X1[4] << 16);
        d[5] = (X0[0] >> 16) | (X0[1] & 0xffff0000u);
        d[6] = (X0[2] >> 16) | (X0[3] & 0xffff0000u);
        d[7] = (X0[4] >> 16) | (X1[0] & 0xffff0000u);
        d[8] = (X1[1] >> 16) | (X1[2] & 0xffff0000u);
        d[9] = (X1[3] >> 16) | (X1[4] & 0xffff0000u);
        d[10] = d[0]; d[11] = d[1]; d[12] = d[2]; d[13] = d[3]; d[14] = d[4];
        d[15] = 0u;
        unsigned int* row = (unsigned int*)&A1[t * A1S];
        #pragma unroll
        for (int ch = 0; ch < 4; ++ch)
            *(uint4*)(row + ch * 4) = make_uint4(d[ch*4], d[ch*4+1], d[ch*4+2], d[ch*4+3]);
    }
    __syncthreads();

    // conv1 via 16x16x32 MFMA: wave wv handles m-tiles wv, wv+4, wv+8, wv+12
    for (int mt = wv; mt < 13; mt += 4) {
        const short8 a = *(const short8*)&A1[(mt * 16 + ml) * A1S + q * 8];
        float4v c0 = {0.f, 0.f, 0.f, 0.f};
        float4v c1 = {0.f, 0.f, 0.f, 0.f};
        c0 = __builtin_amdgcn_mfma_f32_16x16x32_bf16(a, w1frag0, c0, 0, 0, 0);
        c1 = __builtin_amdgcn_mfma_f32_16x16x32_bf16(a, w1frag1, c1, 0, 0, 0);
        #pragma unroll
        for (int r = 0; r < 4; ++r) {
            const int m = mt * 16 + q * 4 + r;
            if (m < SLEN) {
                // interleaved: column 2*ml = ic ml (low), 2*ml+1 = ic 16+ml (high)
                *(unsigned int*)&h1p[(2 + m) * H1S + 2 * ml] =
                    pk2(fmaxf(c0[r] + bias1a, 0.f), fmaxf(c1[r] + bias1b, 0.f));
            }
        }
    }
    __syncthreads();

    // conv2 via 32x32x16 MFMA: wave wv owns 32-row tiles {wv, wv+4} of 7
    // A[m=l31][k=h*8+j] at h1p row (m0+l31+kk), col kc*16+h*8 ; B in wf[]
    float total0 = 0.f, total1 = 0.f;
    for (int mt = wv; mt < 7; mt += 4) {
        const int m0 = mt * 32;
        float16v acc0 = {0.f,0.f,0.f,0.f,0.f,0.f,0.f,0.f,0.f,0.f,0.f,0.f,0.f,0.f,0.f,0.f};
        float16v acc1 = {0.f,0.f,0.f,0.f,0.f,0.f,0.f,0.f,0.f,0.f,0.f,0.f,0.f,0.f,0.f,0.f};
        #pragma unroll
        for (int kk = 0; kk < 5; ++kk) {
            #pragma unroll
            for (int kc = 0; kc < 2; ++kc) {
                const short8 a = *(const short8*)
                    &h1p[(2 + m0 + l31 + kk) * H1S + kc * 16 + h * 8];
                acc0 = __builtin_amdgcn_mfma_f32_32x32x16_bf16(a, wf[(kk*2+kc)*2+0], acc0, 0, 0, 0);
                acc1 = __builtin_amdgcn_mfma_f32_32x32x16_bf16(a, wf[(kk*2+kc)*2+1], acc1, 0, 0, 0);
            }
        }
        // C/D: col(oc)=l31, row = (reg&3) + 8*(reg>>2) + 4*h  (+m0)
        if (mt < 6) {
            #pragma unroll
            for (int reg = 0; reg < 16; ++reg) {
                total0 += fmaxf(acc0[reg] + bias2a, 0.f);
                total1 += fmaxf(acc1[reg] + bias2b, 0.f);
            }
        } else {
            #pragma unroll
            for (int reg = 0; reg < 4; ++reg) {   // rows 192..199 only
                total0 += fmaxf(acc0[reg] + bias2a, 0.f);
                total1 += fmaxf(acc1[reg] + bias2b, 0.f);
            }
        }
    }
    total0 += __shfl_xor(total0, 32, 64);
    total1 += __shfl_xor(total1, 32, 64);
    if (lane < 32) {
        red[wv][l31]      = total0;
        red[wv][32 + l31] = total1;
    }
    __syncthreads();
    if (t < 64)
        hm[t] = (red[0][t] + red[1][t] + red[2][t] + red[3][t]) * (1.0f / 200.0f);
    __syncthreads();

    // fused Wh1 = hm @ W1 (f32), + f1/f2 dots
    {
        const int o = t & 63, q4 = t >> 6;
        const float* Wp = W1 + (q4 * 16) * 64 + o;
        float p = 0.f;
        #pragma unroll
        for (int k = 0; k < 16; ++k) p += hm[q4 * 16 + k] * Wp[k * 64];
        part[q4][o] = p;
    }
    __syncthreads();
    if (t < 64) {
        const float v = part[0][t] + part[1][t] + part[2][t] + part[3][t];
        Wh_bt[((size_t)(b * 64 + t)) * 512 + n] = f2bf(v);
        float v1 = v * a1[t];
        float v2 = v * a1[64 + t];
        #pragma unroll
        for (int off = 32; off; off >>= 1) {
            v1 += __shfl_xor(v1, off, 64);
            v2 += __shfl_xor(v2, off, 64);
        }
        if (t == 0) { f1[b * 512 + n] = v1; f2[b * 512 + n] = v2; }
    }
}

// ---------------------------------------------------------------------------
// Kernel 2: MFMA Wh = h @ W over 64-row tiles (layer 2 only)
// ---------------------------------------------------------------------------
__global__ __launch_bounds__(256) void gat_wh_kernel(
    const float* __restrict__ h,     // (4096, 64)
    const float* __restrict__ W,     // (64, 64)
    const float* __restrict__ a,     // (128, 1)
    u16* __restrict__ Wh_bt,         // (8, 64, 512) bf16
    float* __restrict__ f1,
    float* __restrict__ f2)
{
    __shared__ __align__(16) u16 hA[64 * 72];
    __shared__ __align__(16) u16 Wt[64 * 72];
    __shared__ __align__(16) u16 whT[64 * 72];
    __shared__ float as[128];

    const int t    = threadIdx.x;
    const int blk  = blockIdx.x;
    const int b    = blk >> 3;
    const int j0   = (blk & 7) * 64;
    const int lane = t & 63, wv = t >> 6, ml = lane & 15, q = lane >> 4;

    {
        const int r = t >> 2, c0 = (t & 3) * 16;
        const float* hp = h + ((size_t)(b * 512 + j0 + r)) * 64 + c0;
        #pragma unroll
        for (int v = 0; v < 4; ++v) {
            float4 f = *(const float4*)(hp + v * 4);
            unsigned int* dst = (unsigned int*)&hA[r * 72 + c0 + v * 4];
            dst[0] = pk2(f.x, f.y);
            dst[1] = pk2(f.z, f.w);
        }
    }
    {
        const int k = t >> 2, o0 = (t & 3) * 16;
        const float* wp = W + k * 64 + o0;
        #pragma unroll
        for (int v = 0; v < 16; ++v)
            Wt[(o0 + v) * 72 + k] = f2bf(wp[v]);
    }
    if (t < 128) as[t] = a[t];
    __syncthreads();

    short8 af0 = *(const short8*)&hA[(16 * wv + ml) * 72 + q * 8];
    short8 af1 = *(const short8*)&hA[(16 * wv + ml) * 72 + 32 + q * 8];
    float4v acc[4];
    #pragma unroll
    for (int nt = 0; nt < 4; ++nt) {
        short8 b0 = *(const short8*)&Wt[(16 * nt + ml) * 72 + q * 8];
        short8 b1 = *(const short8*)&Wt[(16 * nt + ml) * 72 + 32 + q * 8];
        float4v c = {0.f, 0.f, 0.f, 0.f};
        c = __builtin_amdgcn_mfma_f32_16x16x32_bf16(af0, b0, c, 0, 0, 0);
        c = __builtin_amdgcn_mfma_f32_16x16x32_bf16(af1, b1, c, 0, 0, 0);
        acc[nt] = c;
    }

    #pragma unroll
    for (int nt = 0; nt < 4; ++nt) {
        unsigned int* dst = (unsigned int*)&whT[(16 * nt + ml) * 72 + 16 * wv + q * 4];
        dst[0] = pk2(acc[nt][0], acc[nt][1]);
        dst[1] = pk2(acc[nt][2], acc[nt][3]);
    }

    #pragma unroll
    for (int r = 0; r < 4; ++r) {
        float v1 = 0.f, v2 = 0.f;
        #pragma unroll
        for (int nt = 0; nt < 4; ++nt) {
            const float w = acc[nt][r];
            v1 += w * as[16 * nt + ml];
            v2 += w * as[64 + 16 * nt + ml];
        }
        v1 += __shfl_xor(v1, 1, 64); v2 += __shfl_xor(v2, 1, 64);
        v1 += __shfl_xor(v1, 2, 64); v2 += __shfl_xor(v2, 2, 64);
        v1 += __shfl_xor(v1, 4, 64); v2 += __shfl_xor(v2, 4, 64);
        v1 += __shfl_xor(v1, 8, 64); v2 += __shfl_xor(v2, 8, 64);
        if (ml == 0) {
            const int j = j0 + 16 * wv + q * 4 + r;
            f1[b * 512 + j] = v1;
            f2[b * 512 + j] = v2;
        }
    }
    __syncthreads();

    {
        const int o = t >> 2, js = (t & 3) * 16;
        u16* dst = Wh_bt + ((size_t)(b * 64 + o)) * 512 + j0 + js;
        *(short8*)dst = *(const short8*)&whT[o * 72 + js];
    }
}

// ---------------------------------------------------------------------------
// Kernel 3: attention, 16-row i-tiles, 512 threads, k-split phase 2
// ---------------------------------------------------------------------------
#define PSTR 520
__global__ __launch_bounds__(512) void gat_attn_kernel(
    const u16* __restrict__ Wh_bt,   // (8, 64, 512) bf16
    const float* __restrict__ f1,
    const float* __restrict__ f2,
    const int* __restrict__ adj,     // (512, 512)
    float* __restrict__ outp,        // (4096, 64) f32
    const int do_relu)
{
    __shared__ __align__(16) u16 P[16 * PSTR];
    __shared__ float f2s[512];
    __shared__ float invs[16];
    __shared__ float f1s[16];
    __shared__ float accH[4][64][4];

    const int t   = threadIdx.x;
    const int blk = blockIdx.x;
    const int b   = blk >> 5;
    const int i0  = (blk & 31) * 16;

    f2s[t & 511] = f2[b * 512 + (t & 511)];
    if (t < 16) f1s[t] = f1[b * 512 + i0 + t];
    __syncthreads();

    {
        const int i = t >> 5, jseg = t & 31;
        const float f1i = f1s[i];
        const int* arow = adj + (size_t)(i0 + i) * 512 + jseg * 16;
        const float* f2p = f2s + jseg * 16;
        float ev[16];
        float mx = -3.0e38f;
        #pragma unroll
        for (int v = 0; v < 4; ++v) {
            const int4 a4 = *(const int4*)(arow + v * 4);
            #pragma unroll
            for (int u = 0; u < 4; ++u) {
                const int msk = (&a4.x)[u];
                float e = f1i + f2p[v * 4 + u];
                e = e > 0.f ? e : 0.2f * e;
                e = (msk > 0) ? e : NEGV;
                ev[v * 4 + u] = e;
                mx = fmaxf(mx, e);
            }
        }
        mx = fmaxf(mx, __shfl_xor(mx, 1, 64));
        mx = fmaxf(mx, __shfl_xor(mx, 2, 64));
        mx = fmaxf(mx, __shfl_xor(mx, 4, 64));
        mx = fmaxf(mx, __shfl_xor(mx, 8, 64));
        mx = fmaxf(mx, __shfl_xor(mx, 16, 64));
        float sum = 0.f;
        #pragma unroll
        for (int v = 0; v < 16; ++v) {
            const float ex = __expf(ev[v] - mx);
            ev[v] = ex;
            sum += ex;
        }
        sum += __shfl_xor(sum, 1, 64);
        sum += __shfl_xor(sum, 2, 64);
        sum += __shfl_xor(sum, 4, 64);
        sum += __shfl_xor(sum, 8, 64);
        sum += __shfl_xor(sum, 16, 64);
        if (jseg == 0) invs[i] = 1.0f / sum;
        unsigned int* prow = (unsigned int*)&P[i * PSTR + jseg * 16];
        #pragma unroll
        for (int v = 0; v < 8; ++v)
            prow[v] = pk2(ev[2 * v], ev[2 * v + 1]);
    }
    __syncthreads();

    const int lane = t & 63, wv = t >> 6, nt = wv & 3, kh = wv >> 2;
    const int ml = lane & 15, q = lane >> 4;
    const u16* Bp = Wh_bt + ((size_t)(b * 64 + nt * 16 + ml)) * 512 + kh * 256 + q * 8;
    float4v acc = {0.f, 0.f, 0.f, 0.f};
    #pragma unroll
    for (int ks = 0; ks < 8; ++ks) {
        const short8 afr = *(const short8*)&P[ml * PSTR + kh * 256 + ks * 32 + q * 8];
        const short8 bfr = *(const short8*)(Bp + ks * 32);
        acc = __builtin_amdgcn_mfma_f32_16x16x32_bf16(afr, bfr, acc, 0, 0, 0);
    }
    if (kh == 1) {
        #pragma unroll
        for (int r = 0; r < 4; ++r) accH[nt][lane][r] = acc[r];
    }
    __syncthreads();
    if (kh == 0) {
        #pragma unroll
        for (int r = 0; r < 4; ++r) {
            const int i2 = q * 4 + r;
            float val = (acc[r] + accH[nt][lane][r]) * invs[i2];
            if (do_relu) val = fmaxf(val, 0.f);
            outp[((size_t)(b * 512 + i0 + i2)) * 64 + nt * 16 + ml] = val;
        }
    }
}

// ---------------------------------------------------------------------------
// Kernel 4: edge MLP via MFMA, 16 edges/block
// ---------------------------------------------------------------------------
#define FSTR 136
__global__ __launch_bounds__(256) void edge_mlp_kernel(
    const float* __restrict__ hg,       // (4096, 64)
    const int* __restrict__ eidx,       // (2048, 2)
    const float* __restrict__ fc1w,     // (128, 64)
    const float* __restrict__ fc1b,     // (64,)
    const float* __restrict__ fc2w,     // (64, 1)
    const float* __restrict__ fc2b,     // (1,)
    float* __restrict__ out)            // (8, 2048)
{
    __shared__ __align__(16) u16 fwT[64 * FSTR];
    __shared__ __align__(16) u16 he[16 * FSTR];
    __shared__ float part[16][4];
    __shared__ float b1s[64], w2s[64];

    const int t   = threadIdx.x;
    const int blk = blockIdx.x;
    const int b   = blk >> 7;
    const int e0  = (blk & 127) * 16;

    {
        const int k = t >> 1, o0 = (t & 1) * 32;
        const float* wp = fc1w + k * 64 + o0;
        #pragma unroll
        for (int v = 0; v < 32; ++v)
            fwT[(o0 + v) * FSTR + k] = f2bf(wp[v]);
    }
    if (t < 64) { b1s[t] = fc1b[t]; w2s[t] = fc2w[t]; }
    {
        const int ep = t >> 4, p = t & 15;
        const int e = e0 + ep;
        const int node = (p < 8) ? eidx[e * 2] : eidx[e * 2 + 1];
        const int c0 = (p & 7) * 8;
        const float* hp = hg + ((size_t)(b * 512 + node)) * 64 + c0;
        const float4 fa = *(const float4*)hp;
        const float4 fb = *(const float4*)(hp + 4);
        unsigned int* dst = (unsigned int*)&he[ep * FSTR + ((p < 8) ? 0 : 64) + c0];
        dst[0] = pk2(fa.x, fa.y);
        dst[1] = pk2(fa.z, fa.w);
        dst[2] = pk2(fb.x, fb.y);
        dst[3] = pk2(fb.z, fb.w);
    }
    __syncthreads();

    const int lane = t & 63, wv = t >> 6, ml = lane & 15, q = lane >> 4;
    float4v acc = {0.f, 0.f, 0.f, 0.f};
    #pragma unroll
    for (int ks = 0; ks < 4; ++ks) {
        const short8 afr = *(const short8*)&he[ml * FSTR + ks * 32 + q * 8];
        const short8 bfr = *(const short8*)&fwT[(16 * wv + ml) * FSTR + ks * 32 + q * 8];
        acc = __builtin_amdgcn_mfma_f32_16x16x32_bf16(afr, bfr, acc, 0, 0, 0);
    }
    const int o = 16 * wv + ml;
    const float bo = b1s[o], wo = w2s[o];
    #pragma unroll
    for (int r = 0; r < 4; ++r) {
        float z = fmaxf(acc[r] + bo, 0.f) * wo;
        z += __shfl_xor(z, 1, 64);
        z += __shfl_xor(z, 2, 64);
        z += __shfl_xor(z, 4, 64);
        z += __shfl_xor(z, 8, 64);
        if (ml == 0) part[q * 4 + r][wv] = z;
    }
    __syncthreads();
    if (t < 16) {
        const float v = part[t][0] + part[t][1] + part[t][2] + part[t][3] + fc2b[0];
        out[b * 2048 + e0 + t] = 1.0f / (1.0f + __expf(-v));
    }
}

// ---------------------------------------------------------------------------
extern "C" void kernel_launch(void* const* d_in, const int* in_sizes, int n_in,
                              void* d_out, int out_size, void* d_ws, size_t ws_size,
                              hipStream_t stream) {
    const float* x    = (const float*)d_in[0];
    const int* adj    = (const int*)d_in[1];
    const int* eidx   = (const int*)d_in[2];
    const float* w1   = (const float*)d_in[3];
    const float* b1   = (const float*)d_in[4];
    const float* w2   = (const float*)d_in[5];
    const float* b2   = (const float*)d_in[6];
    const float* W1   = (const float*)d_in[7];
    const float* a1   = (const float*)d_in[8];
    const float* W2   = (const float*)d_in[9];
    const float* a2   = (const float*)d_in[10];
    const float* fc1w = (const float*)d_in[11];
    const float* fc1b = (const float*)d_in[12];
    const float* fc2w = (const float*)d_in[13];
    const float* fc2b = (const float*)d_in[14];
    float* out = (float*)d_out;

    float* ws = (float*)d_ws;
    const size_t R = (size_t)BATCH * NNODE;       // 4096
    float* g    = ws;                             // R*64 f32 (g1 then g2)
    float* f1   = g + R * 64;                     // R
    float* f2   = f1 + R;                         // R
    u16*   whbt = (u16*)(f2 + R);                 // R*64 bf16
    u16*   w1f  = whbt + R * 64;                  // 1024
    u16*   w2f  = w1f + 1024;                     // 10240
    float* xT   = (float*)(w2f + 10240);          // 8*1024*200 f32

    transpose_kernel<<<dim3(32, 7, 8), dim3(256), 0, stream>>>(x, xT);
    prep_kernel<<<dim3(1), dim3(256), 0, stream>>>(w1, w2, w1f, w2f);
    conv_fused_kernel<<<dim3(R), dim3(256), 0, stream>>>(
        xT, b1, b2, W1, a1, w1f, w2f, whbt, f1, f2);
    gat_attn_kernel<<<dim3(256), dim3(512), 0, stream>>>(whbt, f1, f2, adj, g, 1);
    gat_wh_kernel<<<dim3(64), dim3(256), 0, stream>>>(g, W2, a2, whbt, f1, f2);
    gat_attn_kernel<<<dim3(256), dim3(512), 0, stream>>>(whbt, f1, f2, adj, g, 0);
    edge_mlp_kernel<<<dim3(1024), dim3(256), 0, stream>>>(
        g, eidx, fc1w, fc1b, fc2w, fc2b, out);
}

// Round 10
// 151.400 us; speedup vs baseline: 1.0080x; 1.0080x over previous
//
#include <hip/hip_runtime.h>
#include <hip/hip_bf16.h>

typedef unsigned short u16;
typedef __attribute__((ext_vector_type(8))) short short8;
typedef __attribute__((ext_vector_type(4))) float float4v;
typedef __attribute__((ext_vector_type(16))) float float16v;

#define BATCH 8
#define SLEN  200
#define NNODE 512
#define NEDGE 2048
#define NEGV  -9000000000000000.0f

#define H1S 40    // h1p row stride in bf16 (80 B; 20-dword bank shift/row)
#define H1R 232   // per node: 2 pad + 200 data + 30 pad
#define A1S 40    // im2col row stride in bf16

__device__ __forceinline__ u16 f2bf(float f) {
    unsigned int x = __float_as_uint(f);
    unsigned int lsb = (x >> 16) & 1u;
    x += 0x7fffu + lsb;
    return (u16)(x >> 16);
}

__device__ __forceinline__ float bf2f(u16 u) {
    return __uint_as_float(((unsigned int)u) << 16);
}

__device__ __forceinline__ unsigned int pk2(float a, float b) {
    __hip_bfloat162 h = __float22bfloat162_rn(make_float2(a, b));
    unsigned int r;
    __builtin_memcpy(&r, &h, 4);
    return r;
}

// ---------------------------------------------------------------------------
// pre_kernel: blocks 0..1791 = tiled transpose x -> xT ; block 1792 = weight
// fragment packing (w1f conv1, w2f conv2 32x32, efw edge-fc1).
// ---------------------------------------------------------------------------
__global__ __launch_bounds__(256) void pre_kernel(
    const float* __restrict__ x,     // (8, 200, 1024)
    const float* __restrict__ w1,    // (32, 2, 5)
    const float* __restrict__ w2,    // (64, 32, 5)
    const float* __restrict__ fc1w,  // (128, 64)
    float* __restrict__ xT,          // (8, 1024, 200)
    u16* __restrict__ w1f,           // 2*64*8
    u16* __restrict__ w2f,           // 20*64*8
    u16* __restrict__ efw)           // 16*64*8
{
    __shared__ float tile[32][33];
    const int t = threadIdx.x;
    const int blk = blockIdx.x;

    if (blk < 1792) {
        const int xi  = blk & 31;
        const int rem = blk >> 5;          // 0..55
        const int yi  = rem % 7;
        const int zi  = rem / 7;
        const int nc0 = xi * 32;
        const int s0  = yi * 32;
        const int c   = t & 31, rr = t >> 5;
        #pragma unroll
        for (int r = 0; r < 4; ++r) {
            const int s = s0 + rr + r * 8;
            if (s < SLEN)
                tile[rr + r * 8][c] = x[((size_t)(zi * SLEN + s)) * 1024 + nc0 + c];
        }
        __syncthreads();
        #pragma unroll
        for (int r = 0; r < 4; ++r) {
            const int nc = nc0 + rr + r * 8;
            const int s = s0 + c;
            if (s < SLEN)
                xT[((size_t)(zi * 1024 + nc)) * SLEN + s] = tile[c][rr + r * 8];
        }
        return;
    }

    // ---- prep block ----
    const int lane = t & 63, wv = t >> 6;
    const int ml = lane & 15, q = lane >> 4;
    const int l31 = lane & 31, h = lane >> 5;

    if (t < 128) {
        const int nt = t >> 6;
        const int l  = t & 63;
        const int mml = l & 15, qq = l >> 4;
        const int oc = nt * 16 + mml;
        #pragma unroll
        for (int j = 0; j < 8; ++j) {
            const int k = qq * 8 + j;
            u16 val = 0;
            if (k < 10) {
                val = f2bf(w1[oc * 10 + k]);
            } else if (k < 20) {
                val = f2bf(w1[oc * 10 + (k - 10)]);
            } else if (k < 30) {
                const float wf = w1[oc * 10 + (k - 20)];
                val = f2bf(wf - bf2f(f2bf(wf)));
            }
            w1f[(nt * 64 + l) * 8 + j] = val;
        }
    }
    // conv2 32x32 B-frags: fid = (kk*2+kc)*2+nt
    for (int fid = wv; fid < 20; fid += 4) {
        const int kk = fid >> 2, kc = (fid >> 1) & 1, nt = fid & 1;
        const int oc = nt * 32 + l31;
        #pragma unroll
        for (int j = 0; j < 8; ++j) {
            const int c  = kc * 16 + h * 8 + j;
            const int ic = (c & 1) * 16 + (c >> 1);
            w2f[(fid * 64 + lane) * 8 + j] = f2bf(w2[(size_t)oc * 160 + ic * 5 + kk]);
        }
    }
    // edge fc1 B-frags: unit u = ks*4 + wvv ; oc = wvv*16+ml, k = ks*32+q*8+j
    for (int u = wv; u < 16; u += 4) {
        const int ks = u >> 2, wvv = u & 3;
        const int o = wvv * 16 + ml;
        #pragma unroll
        for (int j = 0; j < 8; ++j) {
            const int k = ks * 32 + q * 8 + j;
            efw[(u * 64 + lane) * 8 + j] = f2bf(fc1w[k * 64 + o]);
        }
    }
}

// ---------------------------------------------------------------------------
// conv_fused_kernel: 2 nodes per block. conv1(16x16x32) -> relu ->
// conv2(32x32x16) -> relu -> mean -> Wh1/f1/f2.  grid 2048 x 256 thr.
// ---------------------------------------------------------------------------
__global__ __launch_bounds__(256) void conv_fused_kernel(
    const float* __restrict__ xT,   // (8, 1024, 200)
    const float* __restrict__ b1,   // (32,)
    const float* __restrict__ b2,   // (64,)
    const float* __restrict__ W1,   // (64, 64)
    const float* __restrict__ a1,   // (128, 1)
    const u16* __restrict__ w1f,
    const u16* __restrict__ w2f,
    u16* __restrict__ Wh_bt,        // (8, 64, 512) bf16 [b][o][node]
    float* __restrict__ f1,         // (4096,)
    float* __restrict__ f2)         // (4096,)
{
    __shared__ unsigned int xhl[2][2][212];          // [node][ch][s+2] (hi|lo<<16)
    __shared__ __align__(16) u16 A1[208 * A1S];      // im2col (reused per node)
    __shared__ __align__(16) u16 h1p[2 * H1R * H1S]; // conv1 out, both nodes
    __shared__ float red[4][2][64];
    __shared__ float hm[2][64];
    __shared__ float part[2][4][64];

    const int t    = threadIdx.x;
    const int blk  = blockIdx.x;
    const int b    = blk >> 8;
    const int pair = blk & 255;
    const int n0   = pair * 2;
    const int lane = t & 63;
    const int wv   = t >> 6;
    const int ml   = lane & 15;
    const int q    = lane >> 4;
    const int l31  = lane & 31;
    const int h    = lane >> 5;

    // prepacked fragments (coalesced 16B, L2-hot)
    const short8 w1frag0 = *(const short8*)(w1f + lane * 8);
    const short8 w1frag1 = *(const short8*)(w1f + (64 + lane) * 8);
    short8 wf[20];
    #pragma unroll
    for (int fid = 0; fid < 20; ++fid)
        wf[fid] = *(const short8*)(w2f + (fid * 64 + lane) * 8);
    const float bias1a = b1[ml];
    const float bias1b = b1[16 + ml];
    const float bias2a = b2[l31];
    const float bias2b = b2[32 + l31];

    // stage x for both nodes (4 contiguous xT rows), split hi/lo; zero pads
    if (t < SLEN) {
        const float* xp = xT + ((size_t)(b * 1024 + 4 * pair)) * SLEN + t;
        #pragma unroll
        for (int u = 0; u < 4; ++u) {          // u = nd*2 + ch
            const float xv = xp[u * SLEN];
            const u16 hi = f2bf(xv);
            const u16 lo = f2bf(xv - bf2f(hi));
            xhl[u >> 1][u & 1][2 + t] = (unsigned int)hi | ((unsigned int)lo << 16);
        }
    } else if (t < 212) {
        const int p = (t < 202) ? (t - 200) : t;   // 0,1, then 202..211
        xhl[0][0][p] = 0u; xhl[0][1][p] = 0u;
        xhl[1][0][p] = 0u; xhl[1][1][p] = 0u;
    }
    // zero h1p pad rows per node: rows 0,1 (dw 0..39) and 202..231 (dw 4040..4639)
    {
        unsigned int* hz = (unsigned int*)h1p;
        for (int idx = t; idx < 1280; idx += 256) {
            const int nd = idx >= 640;
            const int i2 = idx - nd * 640;
            hz[nd * 4640 + ((i2 < 40) ? i2 : (4000 + i2))] = 0u;
        }
    }
    __syncthreads();

    for (int nd = 0; nd < 2; ++nd) {
        // build im2col row m = t
        if (t < 208) {
            unsigned int X0[5], X1[5];
            #pragma unroll
            for (int kk = 0; kk < 5; ++kk) {
                X0[kk] = xhl[nd][0][t + kk];
                X1[kk] = xhl[nd][1][t + kk];
            }
            unsigned int d[16];
            d[0] = (X0[0] & 0xffffu) | (X0[1] << 16);
            d[1] = (X0[2] & 0xffffu) | (X0[3] << 16);
            d[2] = (X0[4] & 0xffffu) | (X1[0] << 16);
            d[3] = (X1[1] & 0xffffu) | (X1[2] << 16);
            d[4] = (X1[3] & 0xffffu) | (X1[4] << 16);
            d[5] = (X0[0] >> 16) | (X0[1] & 0xffff0000u);
            d[6] = (X0[2] >> 16) | (X0[3] & 0xffff0000u);
            d[7] = (X0[4] >> 16) | (X1[0] & 0xffff0000u);
            d[8] = (X1[1] >> 16) | (X1[2] & 0xffff0000u);
            d[9] = (X1[3] >> 16) | (X1[4] & 0xffff0000u);
            d[10] = d[0]; d[11] = d[1]; d[12] = d[2]; d[13] = d[3]; d[14] = d[4];
            d[15] = 0u;
            unsigned int* row = (unsigned int*)&A1[t * A1S];
            #pragma unroll
            for (int ch = 0; ch < 4; ++ch)
                *(uint4*)(row + ch * 4) = make_uint4(d[ch*4], d[ch*4+1], d[ch*4+2], d[ch*4+3]);
        }
        __syncthreads();

        // conv1 via 16x16x32 MFMA
        for (int mt = wv; mt < 13; mt += 4) {
            const short8 a = *(const short8*)&A1[(mt * 16 + ml) * A1S + q * 8];
            float4v c0 = {0.f, 0.f, 0.f, 0.f};
            float4v c1 = {0.f, 0.f, 0.f, 0.f};
            c0 = __builtin_amdgcn_mfma_f32_16x16x32_bf16(a, w1frag0, c0, 0, 0, 0);
            c1 = __builtin_amdgcn_mfma_f32_16x16x32_bf16(a, w1frag1, c1, 0, 0, 0);
            #pragma unroll
            for (int r = 0; r < 4; ++r) {
                const int m = mt * 16 + q * 4 + r;
                if (m < SLEN) {
                    *(unsigned int*)&h1p[(nd * H1R + 2 + m) * H1S + 2 * ml] =
                        pk2(fmaxf(c0[r] + bias1a, 0.f), fmaxf(c1[r] + bias1b, 0.f));
                }
            }
        }
        __syncthreads();
    }

    // conv2 via 32x32x16 MFMA: 14 tiles (7 per node) over 4 waves
    // A-row = nd*H1R + m0 + l31 + kk  (position m0+l31+kk-2 : pad-folded, FIXED)
    float tot00 = 0.f, tot01 = 0.f, tot10 = 0.f, tot11 = 0.f;
    for (int tile = wv; tile < 14; tile += 4) {
        const int nd = (tile >= 7);
        const int mt = nd ? (tile - 7) : tile;
        const int m0 = mt * 32;
        const int rbase = nd * H1R + m0 + l31;
        float16v acc0 = {0.f,0.f,0.f,0.f,0.f,0.f,0.f,0.f,0.f,0.f,0.f,0.f,0.f,0.f,0.f,0.f};
        float16v acc1 = {0.f,0.f,0.f,0.f,0.f,0.f,0.f,0.f,0.f,0.f,0.f,0.f,0.f,0.f,0.f,0.f};
        #pragma unroll
        for (int kk = 0; kk < 5; ++kk) {
            #pragma unroll
            for (int kc = 0; kc < 2; ++kc) {
                const short8 a = *(const short8*)
                    &h1p[(rbase + kk) * H1S + kc * 16 + h * 8];
                acc0 = __builtin_amdgcn_mfma_f32_32x32x16_bf16(a, wf[(kk*2+kc)*2+0], acc0, 0, 0, 0);
                acc1 = __builtin_amdgcn_mfma_f32_32x32x16_bf16(a, wf[(kk*2+kc)*2+1], acc1, 0, 0, 0);
            }
        }
        float s0 = 0.f, s1 = 0.f;
        if (mt < 6) {
            #pragma unroll
            for (int reg = 0; reg < 16; ++reg) {
                s0 += fmaxf(acc0[reg] + bias2a, 0.f);
                s1 += fmaxf(acc1[reg] + bias2b, 0.f);
            }
        } else {
            #pragma unroll
            for (int reg = 0; reg < 4; ++reg) {   // rows 192..199 only
                s0 += fmaxf(acc0[reg] + bias2a, 0.f);
                s1 += fmaxf(acc1[reg] + bias2b, 0.f);
            }
        }
        if (nd == 0) { tot00 += s0; tot01 += s1; }
        else         { tot10 += s0; tot11 += s1; }
    }
    tot00 += __shfl_xor(tot00, 32, 64);
    tot01 += __shfl_xor(tot01, 32, 64);
    tot10 += __shfl_xor(tot10, 32, 64);
    tot11 += __shfl_xor(tot11, 32, 64);
    if (lane < 32) {
        red[wv][0][l31]      = tot00;
        red[wv][0][32 + l31] = tot01;
        red[wv][1][l31]      = tot10;
        red[wv][1][32 + l31] = tot11;
    }
    __syncthreads();
    if (t < 128) {
        const int nd = t >> 6, o = t & 63;
        hm[nd][o] = (red[0][nd][o] + red[1][nd][o] + red[2][nd][o] + red[3][nd][o])
                    * (1.0f / 200.0f);
    }
    __syncthreads();

    // fused Wh1 = hm @ W1 (f32), both nodes share the W1 loads
    {
        const int o = t & 63, q4 = t >> 6;
        const float* Wp = W1 + (q4 * 16) * 64 + o;
        float p0 = 0.f, p1 = 0.f;
        #pragma unroll
        for (int k = 0; k < 16; ++k) {
            const float w = Wp[k * 64];
            p0 += hm[0][q4 * 16 + k] * w;
            p1 += hm[1][q4 * 16 + k] * w;
        }
        part[0][q4][o] = p0;
        part[1][q4][o] = p1;
    }
    __syncthreads();
    if (t < 128) {
        const int nd = t >> 6, o = t & 63;
        const int n = n0 + nd;
        const float v = part[nd][0][o] + part[nd][1][o] + part[nd][2][o] + part[nd][3][o];
        Wh_bt[((size_t)(b * 64 + o)) * 512 + n] = f2bf(v);
        float v1 = v * a1[o];
        float v2 = v * a1[64 + o];
        #pragma unroll
        for (int off = 32; off; off >>= 1) {
            v1 += __shfl_xor(v1, off, 64);
            v2 += __shfl_xor(v2, off, 64);
        }
        if (o == 0) { f1[b * 512 + n] = v1; f2[b * 512 + n] = v2; }
    }
}

// ---------------------------------------------------------------------------
// Kernel 2: MFMA Wh = h @ W over 64-row tiles (layer 2 only)
// ---------------------------------------------------------------------------
__global__ __launch_bounds__(256) void gat_wh_kernel(
    const float* __restrict__ h,     // (4096, 64)
    const float* __restrict__ W,     // (64, 64)
    const float* __restrict__ a,     // (128, 1)
    u16* __restrict__ Wh_bt,         // (8, 64, 512) bf16
    float* __restrict__ f1,
    float* __restrict__ f2)
{
    __shared__ __align__(16) u16 hA[64 * 72];
    __shared__ __align__(16) u16 Wt[64 * 72];
    __shared__ __align__(16) u16 whT[64 * 72];
    __shared__ float as[128];

    const int t    = threadIdx.x;
    const int blk  = blockIdx.x;
    const int b    = blk >> 3;
    const int j0   = (blk & 7) * 64;
    const int lane = t & 63, wv = t >> 6, ml = lane & 15, q = lane >> 4;

    {
        const int r = t >> 2, c0 = (t & 3) * 16;
        const float* hp = h + ((size_t)(b * 512 + j0 + r)) * 64 + c0;
        #pragma unroll
        for (int v = 0; v < 4; ++v) {
            float4 f = *(const float4*)(hp + v * 4);
            unsigned int* dst = (unsigned int*)&hA[r * 72 + c0 + v * 4];
            dst[0] = pk2(f.x, f.y);
            dst[1] = pk2(f.z, f.w);
        }
    }
    {
        const int k = t >> 2, o0 = (t & 3) * 16;
        const float* wp = W + k * 64 + o0;
        #pragma unroll
        for (int v = 0; v < 16; ++v)
            Wt[(o0 + v) * 72 + k] = f2bf(wp[v]);
    }
    if (t < 128) as[t] = a[t];
    __syncthreads();

    short8 af0 = *(const short8*)&hA[(16 * wv + ml) * 72 + q * 8];
    short8 af1 = *(const short8*)&hA[(16 * wv + ml) * 72 + 32 + q * 8];
    float4v acc[4];
    #pragma unroll
    for (int nt = 0; nt < 4; ++nt) {
        short8 b0 = *(const short8*)&Wt[(16 * nt + ml) * 72 + q * 8];
        short8 b1 = *(const short8*)&Wt[(16 * nt + ml) * 72 + 32 + q * 8];
        float4v c = {0.f, 0.f, 0.f, 0.f};
        c = __builtin_amdgcn_mfma_f32_16x16x32_bf16(af0, b0, c, 0, 0, 0);
        c = __builtin_amdgcn_mfma_f32_16x16x32_bf16(af1, b1, c, 0, 0, 0);
        acc[nt] = c;
    }

    #pragma unroll
    for (int nt = 0; nt < 4; ++nt) {
        unsigned int* dst = (unsigned int*)&whT[(16 * nt + ml) * 72 + 16 * wv + q * 4];
        dst[0] = pk2(acc[nt][0], acc[nt][1]);
        dst[1] = pk2(acc[nt][2], acc[nt][3]);
    }

    #pragma unroll
    for (int r = 0; r < 4; ++r) {
        float v1 = 0.f, v2 = 0.f;
        #pragma unroll
        for (int nt = 0; nt < 4; ++nt) {
            const float w = acc[nt][r];
            v1 += w * as[16 * nt + ml];
            v2 += w * as[64 + 16 * nt + ml];
        }
        v1 += __shfl_xor(v1, 1, 64); v2 += __shfl_xor(v2, 1, 64);
        v1 += __shfl_xor(v1, 2, 64); v2 += __shfl_xor(v2, 2, 64);
        v1 += __shfl_xor(v1, 4, 64); v2 += __shfl_xor(v2, 4, 64);
        v1 += __shfl_xor(v1, 8, 64); v2 += __shfl_xor(v2, 8, 64);
        if (ml == 0) {
            const int j = j0 + 16 * wv + q * 4 + r;
            f1[b * 512 + j] = v1;
            f2[b * 512 + j] = v2;
        }
    }
    __syncthreads();

    {
        const int o = t >> 2, js = (t & 3) * 16;
        u16* dst = Wh_bt + ((size_t)(b * 64 + o)) * 512 + j0 + js;
        *(short8*)dst = *(const short8*)&whT[o * 72 + js];
    }
}

// ---------------------------------------------------------------------------
// Kernel 3: attention, 16-row i-tiles, 512 threads, k-split phase 2
// ---------------------------------------------------------------------------
#define PSTR 520
__global__ __launch_bounds__(512) void gat_attn_kernel(
    const u16* __restrict__ Wh_bt,   // (8, 64, 512) bf16
    const float* __restrict__ f1,
    const float* __restrict__ f2,
    const int* __restrict__ adj,     // (512, 512)
    float* __restrict__ outp,        // (4096, 64) f32
    const int do_relu)
{
    __shared__ __align__(16) u16 P[16 * PSTR];
    __shared__ float f2s[512];
    __shared__ float invs[16];
    __shared__ float f1s[16];
    __shared__ float accH[4][64][4];

    const int t   = threadIdx.x;
    const int blk = blockIdx.x;
    const int b   = blk >> 5;
    const int i0  = (blk & 31) * 16;

    f2s[t & 511] = f2[b * 512 + (t & 511)];
    if (t < 16) f1s[t] = f1[b * 512 + i0 + t];
    __syncthreads();

    {
        const int i = t >> 5, jseg = t & 31;
        const float f1i = f1s[i];
        const int* arow = adj + (size_t)(i0 + i) * 512 + jseg * 16;
        const float* f2p = f2s + jseg * 16;
        float ev[16];
        float mx = -3.0e38f;
        #pragma unroll
        for (int v = 0; v < 4; ++v) {
            const int4 a4 = *(const int4*)(arow + v * 4);
            #pragma unroll
            for (int u = 0; u < 4; ++u) {
                const int msk = (&a4.x)[u];
                float e = f1i + f2p[v * 4 + u];
                e = e > 0.f ? e : 0.2f * e;
                e = (msk > 0) ? e : NEGV;
                ev[v * 4 + u] = e;
                mx = fmaxf(mx, e);
            }
        }
        mx = fmaxf(mx, __shfl_xor(mx, 1, 64));
        mx = fmaxf(mx, __shfl_xor(mx, 2, 64));
        mx = fmaxf(mx, __shfl_xor(mx, 4, 64));
        mx = fmaxf(mx, __shfl_xor(mx, 8, 64));
        mx = fmaxf(mx, __shfl_xor(mx, 16, 64));
        float sum = 0.f;
        #pragma unroll
        for (int v = 0; v < 16; ++v) {
            const float ex = __expf(ev[v] - mx);
            ev[v] = ex;
            sum += ex;
        }
        sum += __shfl_xor(sum, 1, 64);
        sum += __shfl_xor(sum, 2, 64);
        sum += __shfl_xor(sum, 4, 64);
        sum += __shfl_xor(sum, 8, 64);
        sum += __shfl_xor(sum, 16, 64);
        if (jseg == 0) invs[i] = 1.0f / sum;
        unsigned int* prow = (unsigned int*)&P[i * PSTR + jseg * 16];
        #pragma unroll
        for (int v = 0; v < 8; ++v)
            prow[v] = pk2(ev[2 * v], ev[2 * v + 1]);
    }
    __syncthreads();

    const int lane = t & 63, wv = t >> 6, nt = wv & 3, kh = wv >> 2;
    const int ml = lane & 15, q = lane >> 4;
    const u16* Bp = Wh_bt + ((size_t)(b * 64 + nt * 16 + ml)) * 512 + kh * 256 + q * 8;
    float4v acc = {0.f, 0.f, 0.f, 0.f};
    #pragma unroll
    for (int ks = 0; ks < 8; ++ks) {
        const short8 afr = *(const short8*)&P[ml * PSTR + kh * 256 + ks * 32 + q * 8];
        const short8 bfr = *(const short8*)(Bp + ks * 32);
        acc = __builtin_amdgcn_mfma_f32_16x16x32_bf16(afr, bfr, acc, 0, 0, 0);
    }
    if (kh == 1) {
        #pragma unroll
        for (int r = 0; r < 4; ++r) accH[nt][lane][r] = acc[r];
    }
    __syncthreads();
    if (kh == 0) {
        #pragma unroll
        for (int r = 0; r < 4; ++r) {
            const int i2 = q * 4 + r;
            float val = (acc[r] + accH[nt][lane][r]) * invs[i2];
            if (do_relu) val = fmaxf(val, 0.f);
            outp[((size_t)(b * 512 + i0 + i2)) * 64 + nt * 16 + ml] = val;
        }
    }
}

// ---------------------------------------------------------------------------
// Kernel 4: edge MLP via MFMA, 16 edges/block, prepacked fc1 B-fragments
// ---------------------------------------------------------------------------
#define FSTR 136
__global__ __launch_bounds__(256) void edge_mlp_kernel(
    const float* __restrict__ hg,       // (4096, 64)
    const int* __restrict__ eidx,       // (2048, 2)
    const u16* __restrict__ efw,        // prepacked fc1 B-frags
    const float* __restrict__ fc1b,     // (64,)
    const float* __restrict__ fc2w,     // (64, 1)
    const float* __restrict__ fc2b,     // (1,)
    float* __restrict__ out)            // (8, 2048)
{
    __shared__ __align__(16) u16 he[16 * FSTR];
    __shared__ float part[16][4];

    const int t   = threadIdx.x;
    const int blk = blockIdx.x;
    const int b   = blk >> 7;
    const int e0  = (blk & 127) * 16;
    const int lane = t & 63, wv = t >> 6, ml = lane & 15, q = lane >> 4;

    // B fragments direct from prepacked global (4 coalesced 16B loads)
    short8 bw[4];
    #pragma unroll
    for (int ks = 0; ks < 4; ++ks)
        bw[ks] = *(const short8*)(efw + ((ks * 4 + wv) * 64 + lane) * 8);
    const int o = 16 * wv + ml;
    const float bo = fc1b[o];
    const float wo = fc2w[o];

    // gather edge features -> LDS bf16
    {
        const int ep = t >> 4, p = t & 15;
        const int e = e0 + ep;
        const int node = (p < 8) ? eidx[e * 2] : eidx[e * 2 + 1];
        const int c0 = (p & 7) * 8;
        const float* hp = hg + ((size_t)(b * 512 + node)) * 64 + c0;
        const float4 fa = *(const float4*)hp;
        const float4 fb = *(const float4*)(hp + 4);
        unsigned int* dst = (unsigned int*)&he[ep * FSTR + ((p < 8) ? 0 : 64) + c0];
        dst[0] = pk2(fa.x, fa.y);
        dst[1] = pk2(fa.z, fa.w);
        dst[2] = pk2(fb.x, fb.y);
        dst[3] = pk2(fb.z, fb.w);
    }
    __syncthreads();

    float4v acc = {0.f, 0.f, 0.f, 0.f};
    #pragma unroll
    for (int ks = 0; ks < 4; ++ks) {
        const short8 afr = *(const short8*)&he[ml * FSTR + ks * 32 + q * 8];
        acc = __builtin_amdgcn_mfma_f32_16x16x32_bf16(afr, bw[ks], acc, 0, 0, 0);
    }
    #pragma unroll
    for (int r = 0; r < 4; ++r) {
        float z = fmaxf(acc[r] + bo, 0.f) * wo;
        z += __shfl_xor(z, 1, 64);
        z += __shfl_xor(z, 2, 64);
        z += __shfl_xor(z, 4, 64);
        z += __shfl_xor(z, 8, 64);
        if (ml == 0) part[q * 4 + r][wv] = z;
    }
    __syncthreads();
    if (t < 16) {
        const float v = part[t][0] + part[t][1] + part[t][2] + part[t][3] + fc2b[0];
        out[b * 2048 + e0 + t] = 1.0f / (1.0f + __expf(-v));
    }
}

// ---------------------------------------------------------------------------
extern "C" void kernel_launch(void* const* d_in, const int* in_sizes, int n_in,
                              void* d_out, int out_size, void* d_ws, size_t ws_size,
                              hipStream_t stream) {
    const float* x    = (const float*)d_in[0];
    const int* adj    = (const int*)d_in[1];
    const int* eidx   = (const int*)d_in[2];
    const float* w1   = (const float*)d_in[3];
    const float* b1   = (const float*)d_in[4];
    const float* w2   = (const float*)d_in[5];
    const float* b2   = (const float*)d_in[6];
    const float* W1   = (const float*)d_in[7];
    const float* a1   = (const float*)d_in[8];
    const float* W2   = (const float*)d_in[9];
    const float* a2   = (const float*)d_in[10];
    const float* fc1w = (const float*)d_in[11];
    const float* fc1b = (const float*)d_in[12];
    const float* fc2w = (const float*)d_in[13];
    const float* fc2b = (const float*)d_in[14];
    float* out = (float*)d_out;

    float* ws = (float*)d_ws;
    const size_t R = (size_t)BATCH * NNODE;       // 4096
    float* g    = ws;                             // R*64 f32 (g1 then g2)
    float* f1   = g + R * 64;                     // R
    float* f2   = f1 + R;                         // R
    u16*   whbt = (u16*)(f2 + R);                 // R*64 bf16
    u16*   w1f  = whbt + R * 64;                  // 1024
    u16*   w2f  = w1f + 1024;                     // 10240
    u16*   efw  = w2f + 10240;                    // 8192
    float* xT   = (float*)(efw + 8192);           // 8*1024*200 f32

    pre_kernel<<<dim3(1793), dim3(256), 0, stream>>>(x, w1, w2, fc1w, xT, w1f, w2f, efw);
    conv_fused_kernel<<<dim3(2048), dim3(256), 0, stream>>>(
        xT, b1, b2, W1, a1, w1f, w2f, whbt, f1, f2);
    gat_attn_kernel<<<dim3(256), dim3(512), 0, stream>>>(whbt, f1, f2, adj, g, 1);
    gat_wh_kernel<<<dim3(64), dim3(256), 0, stream>>>(g, W2, a2, whbt, f1, f2);
    gat_attn_kernel<<<dim3(256), dim3(512), 0, stream>>>(whbt, f1, f2, adj, g, 0);
    edge_mlp_kernel<<<dim3(1024), dim3(256), 0, stream>>>(
        g, eidx, efw, fc1b, fc2w, fc2b, out);
}

// Round 11
// 142.497 us; speedup vs baseline: 1.0710x; 1.0625x over previous
//
#include <hip/hip_runtime.h>
#include <hip/hip_bf16.h>

typedef unsigned short u16;
typedef __attribute__((ext_vector_type(8))) short short8;
typedef __attribute__((ext_vector_type(4))) float float4v;

#define BATCH 8
#define SLEN  200
#define NNODE 512
#define NEDGE 2048
#define NEGV  -9000000000000000.0f

#define H1S 40    // h1p row stride in bf16 (80 B; 20-dword bank shift/row)
#define H1R 212   // 2 pad + 200 data + 10 pad

__device__ __forceinline__ u16 f2bf(float f) {
    unsigned int x = __float_as_uint(f);
    unsigned int lsb = (x >> 16) & 1u;
    x += 0x7fffu + lsb;
    return (u16)(x >> 16);
}

__device__ __forceinline__ float bf2f(u16 u) {
    return __uint_as_float(((unsigned int)u) << 16);
}

__device__ __forceinline__ unsigned int pk2(float a, float b) {
    __hip_bfloat162 h = __float22bfloat162_rn(make_float2(a, b));
    unsigned int r;
    __builtin_memcpy(&r, &h, 4);
    return r;
}

// ---------------------------------------------------------------------------
// pre_kernel: blocks 0..1791 = tiled transpose x -> xT ; block 1792 = weight
// fragment packing (w2f conv2 16x16, efw edge-fc1).
// ---------------------------------------------------------------------------
__global__ __launch_bounds__(256) void pre_kernel(
    const float* __restrict__ x,     // (8, 200, 1024)
    const float* __restrict__ w2,    // (64, 32, 5)
    const float* __restrict__ fc1w,  // (128, 64)
    float* __restrict__ xT,          // (8, 1024, 200)
    u16* __restrict__ w2f,           // 20*64*8
    u16* __restrict__ efw)           // 16*64*8
{
    __shared__ float tile[32][33];
    const int t = threadIdx.x;
    const int blk = blockIdx.x;

    if (blk < 1792) {
        const int xi  = blk & 31;
        const int rem = blk >> 5;          // 0..55
        const int yi  = rem % 7;
        const int zi  = rem / 7;
        const int nc0 = xi * 32;
        const int s0  = yi * 32;
        const int c   = t & 31, rr = t >> 5;
        #pragma unroll
        for (int r = 0; r < 4; ++r) {
            const int s = s0 + rr + r * 8;
            if (s < SLEN)
                tile[rr + r * 8][c] = x[((size_t)(zi * SLEN + s)) * 1024 + nc0 + c];
        }
        __syncthreads();
        #pragma unroll
        for (int r = 0; r < 4; ++r) {
            const int nc = nc0 + rr + r * 8;
            const int s = s0 + c;
            if (s < SLEN)
                xT[((size_t)(zi * 1024 + nc)) * SLEN + s] = tile[c][rr + r * 8];
        }
        return;
    }

    // ---- prep block ----
    const int lane = t & 63, wv = t >> 6;
    const int ml = lane & 15, q = lane >> 4;

    // conv2 16x16 B-frags: fid = kk*4 + ot ; oc = ot*16+ml ; col c = q*8+j,
    // ic = (c&1)*16 + (c>>1)  (interleaved h1p layout)
    for (int fid = wv; fid < 20; fid += 4) {
        const int kk = fid >> 2, ot = fid & 3;
        const int oc = ot * 16 + ml;
        #pragma unroll
        for (int j = 0; j < 8; ++j) {
            const int c  = q * 8 + j;
            const int ic = (c & 1) * 16 + (c >> 1);
            w2f[(fid * 64 + lane) * 8 + j] = f2bf(w2[(size_t)oc * 160 + ic * 5 + kk]);
        }
    }
    // edge fc1 B-frags: unit u = ks*4 + wvv ; oc = wvv*16+ml, k = ks*32+q*8+j
    for (int u = wv; u < 16; u += 4) {
        const int ks = u >> 2, wvv = u & 3;
        const int o = wvv * 16 + ml;
        #pragma unroll
        for (int j = 0; j < 8; ++j) {
            const int k = ks * 32 + q * 8 + j;
            efw[(u * 64 + lane) * 8 + j] = f2bf(fc1w[k * 64 + o]);
        }
    }
}

// ---------------------------------------------------------------------------
// conv_fused_kernel: 1 node/block, 4096 blocks x 256 thr.
// conv1 on VALU (f32) -> h1p bf16 -> conv2 16x16x32 MFMA (2 oc-tiles x
// 2 m-halves per wave) -> relu -> mean -> Wh1/f1/f2.
// LDS ~20 KB for high co-residency (the round-9/10 lesson: occupancy is
// the conv bottleneck, not LDS read count).
// ---------------------------------------------------------------------------
__global__ __launch_bounds__(256) void conv_fused_kernel(
    const float* __restrict__ xT,   // (8, 1024, 200)
    const float* __restrict__ w1,   // (32, 2, 5)
    const float* __restrict__ b1,   // (32,)
    const float* __restrict__ b2,   // (64,)
    const float* __restrict__ W1,   // (64, 64)
    const float* __restrict__ a1,   // (128, 1)
    const u16* __restrict__ w2f,
    u16* __restrict__ Wh_bt,        // (8, 64, 512) bf16 [b][o][node]
    float* __restrict__ f1,         // (4096,)
    float* __restrict__ f2)         // (4096,)
{
    __shared__ float xs[2][212];                    // f32, idx = s+2, pads 0
    __shared__ __align__(16) u16 h1p[H1R * H1S];    // conv1 out [s][c], c=2u+v <-> ic=v*16+u
    __shared__ float red[4][32];
    __shared__ float hm[64];
    __shared__ float part[4][64];

    const int t    = threadIdx.x;
    const int blk  = blockIdx.x;
    const int b    = blk >> 9;
    const int n    = blk & 511;
    const int lane = t & 63;
    const int wv   = t >> 6;
    const int ml   = lane & 15;
    const int q    = lane >> 4;

    // conv1 thread mapping: p = ic-pair (p, 16+p), g = position-group base
    const int p = t & 15;
    const int g = t >> 4;

    // conv2 wave mapping: o2 = oc-half, mh = m-half
    const int o2 = wv & 1;
    const int mh = wv >> 1;

    // prepacked conv2 B-frags (10 x 16B coalesced, L2-hot)
    short8 wfA[5], wfB[5];
    #pragma unroll
    for (int kk = 0; kk < 5; ++kk) {
        wfA[kk] = *(const short8*)(w2f + ((kk * 4 + o2 * 2 + 0) * 64 + lane) * 8);
        wfB[kk] = *(const short8*)(w2f + ((kk * 4 + o2 * 2 + 1) * 64 + lane) * 8);
    }
    const float bias2a = b2[o2 * 32 + ml];
    const float bias2b = b2[o2 * 32 + 16 + ml];

    // conv1 weights (f32, L2-hot broadcast)
    float wA[10], wB[10];
    #pragma unroll
    for (int j = 0; j < 10; ++j) {
        wA[j] = w1[p * 10 + j];
        wB[j] = w1[(16 + p) * 10 + j];
    }
    const float b1a = b1[p], b1b = b1[16 + p];

    // stage x (f32) + zero pads ; zero h1p pad rows 0,1 and 202..211
    if (t < SLEN) {
        const float* xp = xT + ((size_t)(b * 1024 + 2 * n)) * SLEN + t;
        xs[0][2 + t] = xp[0];
        xs[1][2 + t] = xp[SLEN];
    } else if (t < 212) {
        const int pp = (t < 202) ? (t - 200) : t;   // 0,1, then 202..211
        xs[0][pp] = 0.f;
        xs[1][pp] = 0.f;
    }
    {
        unsigned int* hz = (unsigned int*)h1p;
        if (t < 40)       hz[t] = 0u;
        else if (t < 240) hz[4000 + t] = 0u;        // dwords 4040..4239 = rows 202..211
    }
    __syncthreads();

    // conv1 (VALU, f32): thread handles positions {4g + 64u}, 4 consecutive each
    #pragma unroll
    for (int u = 0; u < 4; ++u) {
        const int base = 4 * g + 64 * u;            // 4-aligned, window base..base+7
        if (base < SLEN) {
            float X0[8], X1[8];
            *(float4*)&X0[0] = *(const float4*)&xs[0][base];
            *(float4*)&X0[4] = *(const float4*)&xs[0][base + 4];
            *(float4*)&X1[0] = *(const float4*)&xs[1][base];
            *(float4*)&X1[4] = *(const float4*)&xs[1][base + 4];
            #pragma unroll
            for (int i = 0; i < 4; ++i) {           // position base+i (<= 199)
                float a0 = b1a, a1 = b1b;
                #pragma unroll
                for (int k = 0; k < 5; ++k) {
                    const float x0 = X0[i + k], x1 = X1[i + k];
                    a0 += wA[k] * x0 + wA[5 + k] * x1;
                    a1 += wB[k] * x0 + wB[5 + k] * x1;
                }
                // interleaved: col 2p = ic p, col 2p+1 = ic 16+p
                *(unsigned int*)&h1p[(2 + base + i) * H1S + 2 * p] =
                    pk2(fmaxf(a0, 0.f), fmaxf(a1, 0.f));
            }
        }
    }
    __syncthreads();

    // conv2 via 16x16x32 MFMA: wave = (o2, mh); m-tiles [mh*7, mh?13:7)
    float tA = 0.f, tB = 0.f;
    const int mt0 = mh * 7, mtE = mh ? 13 : 7;
    for (int mt = mt0; mt < mtE; ++mt) {
        float4v acc0 = {0.f, 0.f, 0.f, 0.f};
        float4v acc1 = {0.f, 0.f, 0.f, 0.f};
        #pragma unroll
        for (int kk = 0; kk < 5; ++kk) {
            const short8 a = *(const short8*)&h1p[(mt * 16 + ml + kk) * H1S + q * 8];
            acc0 = __builtin_amdgcn_mfma_f32_16x16x32_bf16(a, wfA[kk], acc0, 0, 0, 0);
            acc1 = __builtin_amdgcn_mfma_f32_16x16x32_bf16(a, wfB[kk], acc1, 0, 0, 0);
        }
        if (mt < 12) {
            #pragma unroll
            for (int r = 0; r < 4; ++r) {
                tA += fmaxf(acc0[r] + bias2a, 0.f);
                tB += fmaxf(acc1[r] + bias2b, 0.f);
            }
        } else if (q < 2) {   // m = 192 + q*4 + r < 200
            #pragma unroll
            for (int r = 0; r < 4; ++r) {
                tA += fmaxf(acc0[r] + bias2a, 0.f);
                tB += fmaxf(acc1[r] + bias2b, 0.f);
            }
        }
    }
    tA += __shfl_xor(tA, 16, 64);
    tA += __shfl_xor(tA, 32, 64);
    tB += __shfl_xor(tB, 16, 64);
    tB += __shfl_xor(tB, 32, 64);
    if (lane < 16) {
        red[wv][ml]      = tA;     // oc = o2*32 + ml
        red[wv][16 + ml] = tB;     // oc = o2*32 + 16 + ml
    }
    __syncthreads();
    if (t < 64) {
        const int grp = t >> 5, idx = t & 31;      // waves grp, grp+2 hold this oc
        hm[t] = (red[grp][idx] + red[grp + 2][idx]) * (1.0f / 200.0f);
    }
    __syncthreads();

    // fused Wh1 = hm @ W1 (f32), + f1/f2 dots
    {
        const int o = t & 63, q4 = t >> 6;
        const float* Wp = W1 + (q4 * 16) * 64 + o;
        float pv = 0.f;
        #pragma unroll
        for (int k = 0; k < 16; ++k) pv += hm[q4 * 16 + k] * Wp[k * 64];
        part[q4][o] = pv;
    }
    __syncthreads();
    if (t < 64) {
        const float v = part[0][t] + part[1][t] + part[2][t] + part[3][t];
        Wh_bt[((size_t)(b * 64 + t)) * 512 + n] = f2bf(v);
        float v1 = v * a1[t];
        float v2 = v * a1[64 + t];
        #pragma unroll
        for (int off = 32; off; off >>= 1) {
            v1 += __shfl_xor(v1, off, 64);
            v2 += __shfl_xor(v2, off, 64);
        }
        if (t == 0) { f1[b * 512 + n] = v1; f2[b * 512 + n] = v2; }
    }
}

// ---------------------------------------------------------------------------
// Kernel 2: MFMA Wh = h @ W over 64-row tiles (layer 2 only)
// ---------------------------------------------------------------------------
__global__ __launch_bounds__(256) void gat_wh_kernel(
    const float* __restrict__ h,     // (4096, 64)
    const float* __restrict__ W,     // (64, 64)
    const float* __restrict__ a,     // (128, 1)
    u16* __restrict__ Wh_bt,         // (8, 64, 512) bf16
    float* __restrict__ f1,
    float* __restrict__ f2)
{
    __shared__ __align__(16) u16 hA[64 * 72];
    __shared__ __align__(16) u16 Wt[64 * 72];
    __shared__ __align__(16) u16 whT[64 * 72];
    __shared__ float as[128];

    const int t    = threadIdx.x;
    const int blk  = blockIdx.x;
    const int b    = blk >> 3;
    const int j0   = (blk & 7) * 64;
    const int lane = t & 63, wv = t >> 6, ml = lane & 15, q = lane >> 4;

    {
        const int r = t >> 2, c0 = (t & 3) * 16;
        const float* hp = h + ((size_t)(b * 512 + j0 + r)) * 64 + c0;
        #pragma unroll
        for (int v = 0; v < 4; ++v) {
            float4 f = *(const float4*)(hp + v * 4);
            unsigned int* dst = (unsigned int*)&hA[r * 72 + c0 + v * 4];
            dst[0] = pk2(f.x, f.y);
            dst[1] = pk2(f.z, f.w);
        }
    }
    {
        const int k = t >> 2, o0 = (t & 3) * 16;
        const float* wp = W + k * 64 + o0;
        #pragma unroll
        for (int v = 0; v < 16; ++v)
            Wt[(o0 + v) * 72 + k] = f2bf(wp[v]);
    }
    if (t < 128) as[t] = a[t];
    __syncthreads();

    short8 af0 = *(const short8*)&hA[(16 * wv + ml) * 72 + q * 8];
    short8 af1 = *(const short8*)&hA[(16 * wv + ml) * 72 + 32 + q * 8];
    float4v acc[4];
    #pragma unroll
    for (int nt = 0; nt < 4; ++nt) {
        short8 b0 = *(const short8*)&Wt[(16 * nt + ml) * 72 + q * 8];
        short8 b1 = *(const short8*)&Wt[(16 * nt + ml) * 72 + 32 + q * 8];
        float4v c = {0.f, 0.f, 0.f, 0.f};
        c = __builtin_amdgcn_mfma_f32_16x16x32_bf16(af0, b0, c, 0, 0, 0);
        c = __builtin_amdgcn_mfma_f32_16x16x32_bf16(af1, b1, c, 0, 0, 0);
        acc[nt] = c;
    }

    #pragma unroll
    for (int nt = 0; nt < 4; ++nt) {
        unsigned int* dst = (unsigned int*)&whT[(16 * nt + ml) * 72 + 16 * wv + q * 4];
        dst[0] = pk2(acc[nt][0], acc[nt][1]);
        dst[1] = pk2(acc[nt][2], acc[nt][3]);
    }

    #pragma unroll
    for (int r = 0; r < 4; ++r) {
        float v1 = 0.f, v2 = 0.f;
        #pragma unroll
        for (int nt = 0; nt < 4; ++nt) {
            const float w = acc[nt][r];
            v1 += w * as[16 * nt + ml];
            v2 += w * as[64 + 16 * nt + ml];
        }
        v1 += __shfl_xor(v1, 1, 64); v2 += __shfl_xor(v2, 1, 64);
        v1 += __shfl_xor(v1, 2, 64); v2 += __shfl_xor(v2, 2, 64);
        v1 += __shfl_xor(v1, 4, 64); v2 += __shfl_xor(v2, 4, 64);
        v1 += __shfl_xor(v1, 8, 64); v2 += __shfl_xor(v2, 8, 64);
        if (ml == 0) {
            const int j = j0 + 16 * wv + q * 4 + r;
            f1[b * 512 + j] = v1;
            f2[b * 512 + j] = v2;
        }
    }
    __syncthreads();

    {
        const int o = t >> 2, js = (t & 3) * 16;
        u16* dst = Wh_bt + ((size_t)(b * 64 + o)) * 512 + j0 + js;
        *(short8*)dst = *(const short8*)&whT[o * 72 + js];
    }
}

// ---------------------------------------------------------------------------
// Kernel 3: attention, 16-row i-tiles, 512 threads, k-split phase 2
// ---------------------------------------------------------------------------
#define PSTR 520
__global__ __launch_bounds__(512) void gat_attn_kernel(
    const u16* __restrict__ Wh_bt,   // (8, 64, 512) bf16
    const float* __restrict__ f1,
    const float* __restrict__ f2,
    const int* __restrict__ adj,     // (512, 512)
    float* __restrict__ outp,        // (4096, 64) f32
    const int do_relu)
{
    __shared__ __align__(16) u16 P[16 * PSTR];
    __shared__ float f2s[512];
    __shared__ float invs[16];
    __shared__ float f1s[16];
    __shared__ float accH[4][64][4];

    const int t   = threadIdx.x;
    const int blk = blockIdx.x;
    const int b   = blk >> 5;
    const int i0  = (blk & 31) * 16;

    f2s[t & 511] = f2[b * 512 + (t & 511)];
    if (t < 16) f1s[t] = f1[b * 512 + i0 + t];
    __syncthreads();

    {
        const int i = t >> 5, jseg = t & 31;
        const float f1i = f1s[i];
        const int* arow = adj + (size_t)(i0 + i) * 512 + jseg * 16;
        const float* f2p = f2s + jseg * 16;
        float ev[16];
        float mx = -3.0e38f;
        #pragma unroll
        for (int v = 0; v < 4; ++v) {
            const int4 a4 = *(const int4*)(arow + v * 4);
            #pragma unroll
            for (int u = 0; u < 4; ++u) {
                const int msk = (&a4.x)[u];
                float e = f1i + f2p[v * 4 + u];
                e = e > 0.f ? e : 0.2f * e;
                e = (msk > 0) ? e : NEGV;
                ev[v * 4 + u] = e;
                mx = fmaxf(mx, e);
            }
        }
        mx = fmaxf(mx, __shfl_xor(mx, 1, 64));
        mx = fmaxf(mx, __shfl_xor(mx, 2, 64));
        mx = fmaxf(mx, __shfl_xor(mx, 4, 64));
        mx = fmaxf(mx, __shfl_xor(mx, 8, 64));
        mx = fmaxf(mx, __shfl_xor(mx, 16, 64));
        float sum = 0.f;
        #pragma unroll
        for (int v = 0; v < 16; ++v) {
            const float ex = __expf(ev[v] - mx);
            ev[v] = ex;
            sum += ex;
        }
        sum += __shfl_xor(sum, 1, 64);
        sum += __shfl_xor(sum, 2, 64);
        sum += __shfl_xor(sum, 4, 64);
        sum += __shfl_xor(sum, 8, 64);
        sum += __shfl_xor(sum, 16, 64);
        if (jseg == 0) invs[i] = 1.0f / sum;
        unsigned int* prow = (unsigned int*)&P[i * PSTR + jseg * 16];
        #pragma unroll
        for (int v = 0; v < 8; ++v)
            prow[v] = pk2(ev[2 * v], ev[2 * v + 1]);
    }
    __syncthreads();

    const int lane = t & 63, wv = t >> 6, nt = wv & 3, kh = wv >> 2;
    const int ml = lane & 15, q = lane >> 4;
    const u16* Bp = Wh_bt + ((size_t)(b * 64 + nt * 16 + ml)) * 512 + kh * 256 + q * 8;
    float4v acc = {0.f, 0.f, 0.f, 0.f};
    #pragma unroll
    for (int ks = 0; ks < 8; ++ks) {
        const short8 afr = *(const short8*)&P[ml * PSTR + kh * 256 + ks * 32 + q * 8];
        const short8 bfr = *(const short8*)(Bp + ks * 32);
        acc = __builtin_amdgcn_mfma_f32_16x16x32_bf16(afr, bfr, acc, 0, 0, 0);
    }
    if (kh == 1) {
        #pragma unroll
        for (int r = 0; r < 4; ++r) accH[nt][lane][r] = acc[r];
    }
    __syncthreads();
    if (kh == 0) {
        #pragma unroll
        for (int r = 0; r < 4; ++r) {
            const int i2 = q * 4 + r;
            float val = (acc[r] + accH[nt][lane][r]) * invs[i2];
            if (do_relu) val = fmaxf(val, 0.f);
            outp[((size_t)(b * 512 + i0 + i2)) * 64 + nt * 16 + ml] = val;
        }
    }
}

// ---------------------------------------------------------------------------
// Kernel 4: edge MLP via MFMA, 16 edges/block, prepacked fc1 B-fragments
// ---------------------------------------------------------------------------
#define FSTR 136
__global__ __launch_bounds__(256) void edge_mlp_kernel(
    const float* __restrict__ hg,       // (4096, 64)
    const int* __restrict__ eidx,       // (2048, 2)
    const u16* __restrict__ efw,        // prepacked fc1 B-frags
    const float* __restrict__ fc1b,     // (64,)
    const float* __restrict__ fc2w,     // (64, 1)
    const float* __restrict__ fc2b,     // (1,)
    float* __restrict__ out)            // (8, 2048)
{
    __shared__ __align__(16) u16 he[16 * FSTR];
    __shared__ float part[16][4];

    const int t   = threadIdx.x;
    const int blk = blockIdx.x;
    const int b   = blk >> 7;
    const int e0  = (blk & 127) * 16;
    const int lane = t & 63, wv = t >> 6, ml = lane & 15, q = lane >> 4;

    short8 bw[4];
    #pragma unroll
    for (int ks = 0; ks < 4; ++ks)
        bw[ks] = *(const short8*)(efw + ((ks * 4 + wv) * 64 + lane) * 8);
    const int o = 16 * wv + ml;
    const float bo = fc1b[o];
    const float wo = fc2w[o];

    {
        const int ep = t >> 4, p = t & 15;
        const int e = e0 + ep;
        const int node = (p < 8) ? eidx[e * 2] : eidx[e * 2 + 1];
        const int c0 = (p & 7) * 8;
        const float* hp = hg + ((size_t)(b * 512 + node)) * 64 + c0;
        const float4 fa = *(const float4*)hp;
        const float4 fb = *(const float4*)(hp + 4);
        unsigned int* dst = (unsigned int*)&he[ep * FSTR + ((p < 8) ? 0 : 64) + c0];
        dst[0] = pk2(fa.x, fa.y);
        dst[1] = pk2(fa.z, fa.w);
        dst[2] = pk2(fb.x, fb.y);
        dst[3] = pk2(fb.z, fb.w);
    }
    __syncthreads();

    float4v acc = {0.f, 0.f, 0.f, 0.f};
    #pragma unroll
    for (int ks = 0; ks < 4; ++ks) {
        const short8 afr = *(const short8*)&he[ml * FSTR + ks * 32 + q * 8];
        acc = __builtin_amdgcn_mfma_f32_16x16x32_bf16(afr, bw[ks], acc, 0, 0, 0);
    }
    #pragma unroll
    for (int r = 0; r < 4; ++r) {
        float z = fmaxf(acc[r] + bo, 0.f) * wo;
        z += __shfl_xor(z, 1, 64);
        z += __shfl_xor(z, 2, 64);
        z += __shfl_xor(z, 4, 64);
        z += __shfl_xor(z, 8, 64);
        if (ml == 0) part[q * 4 + r][wv] = z;
    }
    __syncthreads();
    if (t < 16) {
        const float v = part[t][0] + part[t][1] + part[t][2] + part[t][3] + fc2b[0];
        out[b * 2048 + e0 + t] = 1.0f / (1.0f + __expf(-v));
    }
}

// ---------------------------------------------------------------------------
extern "C" void kernel_launch(void* const* d_in, const int* in_sizes, int n_in,
                              void* d_out, int out_size, void* d_ws, size_t ws_size,
                              hipStream_t stream) {
    const float* x    = (const float*)d_in[0];
    const int* adj    = (const int*)d_in[1];
    const int* eidx   = (const int*)d_in[2];
    const float* w1   = (const float*)d_in[3];
    const float* b1   = (const float*)d_in[4];
    const float* w2   = (const float*)d_in[5];
    const float* b2   = (const float*)d_in[6];
    const float* W1   = (const float*)d_in[7];
    const float* a1   = (const float*)d_in[8];
    const float* W2   = (const float*)d_in[9];
    const float* a2   = (const float*)d_in[10];
    const float* fc1w = (const float*)d_in[11];
    const float* fc1b = (const float*)d_in[12];
    const float* fc2w = (const float*)d_in[13];
    const float* fc2b = (const float*)d_in[14];
    float* out = (float*)d_out;

    float* ws = (float*)d_ws;
    const size_t R = (size_t)BATCH * NNODE;       // 4096
    float* g    = ws;                             // R*64 f32 (g1 then g2)
    float* f1   = g + R * 64;                     // R
    float* f2   = f1 + R;                         // R
    u16*   whbt = (u16*)(f2 + R);                 // R*64 bf16
    u16*   w2f  = whbt + R * 64;                  // 10240
    u16*   efw  = w2f + 10240;                    // 8192
    float* xT   = (float*)(efw + 8192);           // 8*1024*200 f32

    pre_kernel<<<dim3(1793), dim3(256), 0, stream>>>(x, w2, fc1w, xT, w2f, efw);
    conv_fused_kernel<<<dim3(4096), dim3(256), 0, stream>>>(
        xT, w1, b1, b2, W1, a1, w2f, whbt, f1, f2);
    gat_attn_kernel<<<dim3(256), dim3(512), 0, stream>>>(whbt, f1, f2, adj, g, 1);
    gat_wh_kernel<<<dim3(64), dim3(256), 0, stream>>>(g, W2, a2, whbt, f1, f2);
    gat_attn_kernel<<<dim3(256), dim3(512), 0, stream>>>(whbt, f1, f2, adj, g, 0);
    edge_mlp_kernel<<<dim3(1024), dim3(256), 0, stream>>>(
        g, eidx, efw, fc1b, fc2w, fc2b, out);
}